// Round 3
// baseline (558.206 us; speedup 1.0000x reference)
//
#include <hip/hip_runtime.h>

typedef unsigned short u16;
typedef __bf16 bf16x8 __attribute__((ext_vector_type(8)));
typedef float f32x4 __attribute__((ext_vector_type(4)));
typedef u16 u16x4 __attribute__((ext_vector_type(4)));

constexpr int SEQ = 2048;
constexpr int NQKV = 6144; // (32 + 2*8) * 128

__device__ __forceinline__ float bf2f(u16 x) {
    unsigned int u = ((unsigned int)x) << 16;
    return __builtin_bit_cast(float, u);
}
__device__ __forceinline__ u16 f2bf(float f) {
    unsigned int u = __builtin_bit_cast(unsigned int, f);
    u += 0x7FFF + ((u >> 16) & 1);
    return (u16)(u >> 16);
}

__device__ __forceinline__ void gload16(const void* g, void* l) {
    void* gg = const_cast<void*>(g);
    __builtin_amdgcn_global_load_lds(
        (__attribute__((address_space(1))) void*)gg,
        (__attribute__((address_space(3))) void*)l, 16, 0, 0);
}

// ---------------- RoPE table ----------------
__global__ void rope_table_k(float* __restrict__ tab) {
    int idx = blockIdx.x * 256 + threadIdx.x;
    if (idx >= SEQ * 64) return;
    int s = idx >> 6;
    int i = idx & 63;
    float invf = expf(-(float)i * (float)(1.0 / 64.0) * logf(10000.0f));
    float ang = (float)s * invf;
    float sv, cv;
    sincosf(ang, &sv, &cv);
    tab[idx * 2] = cv;
    tab[idx * 2 + 1] = sv;
}

// ---------------- fp32 -> bf16 elementwise cast ----------------
__global__ __launch_bounds__(256) void cast_k(const float* __restrict__ src,
                                              u16* __restrict__ dst, int n4) {
    int i = blockIdx.x * 256 + threadIdx.x;
    if (i >= n4) return;
    f32x4 v = *(const f32x4*)&src[(size_t)i * 4];
    u16x4 o;
#pragma unroll
    for (int j = 0; j < 4; ++j) o[j] = f2bf(v[j]);
    *(u16x4*)&dst[(size_t)i * 4] = o;
}

// ---------------- fp32 transpose+cast (R x C fp32 -> C x R bf16) ----------------
__global__ __launch_bounds__(256) void transpose_cast_k(const float* __restrict__ src,
                                                        u16* __restrict__ dst, int R, int C) {
    __shared__ u16 tile[64][65];
    int t = threadIdx.x;
    int bx = blockIdx.x, by = blockIdx.y;
    int r0 = by * 64, c0 = bx * 64;
#pragma unroll
    for (int it = 0; it < 4; ++it) {
        int row = it * 16 + (t >> 4);
        int col = (t & 15) * 4;
        f32x4 v = *(const f32x4*)&src[(size_t)(r0 + row) * C + c0 + col];
        tile[row][col] = f2bf(v[0]); tile[row][col + 1] = f2bf(v[1]);
        tile[row][col + 2] = f2bf(v[2]); tile[row][col + 3] = f2bf(v[3]);
    }
    __syncthreads();
#pragma unroll
    for (int it = 0; it < 4; ++it) {
        int orow = it * 16 + (t >> 4);
        int ocol = (t & 15) * 4;
        u16x4 v;
        v[0] = tile[ocol][orow]; v[1] = tile[ocol + 1][orow];
        v[2] = tile[ocol + 2][orow]; v[3] = tile[ocol + 3][orow];
        *(u16x4*)&dst[(size_t)(c0 + orow) * R + r0 + ocol] = v;
    }
}

// ---------------- GEMM: C[M,N] = A[M,K] * BT[N,K]^T, bf16 in, fp32 acc ----
template <bool F32OUT>
__global__ __launch_bounds__(256) void gemm_bt_k(const u16* __restrict__ A,
                                                 const u16* __restrict__ BT,
                                                 void* __restrict__ Cv, int N, int K) {
    __shared__ alignas(16) u16 Asw[128 * 32];
    __shared__ alignas(16) u16 Bsw[128 * 32];
    int t = threadIdx.x;
    int lane = t & 63, w = t >> 6;
    int wm = w >> 1, wn = w & 1;
    int l15 = lane & 15, l4 = lane >> 4;

    // XCD-aware swizzle (grids are multiples of 8)
    int nbn = N >> 7;
    int nwg = gridDim.x;
    int wg = blockIdx.x;
    int cpx = nwg >> 3;
    int swz = (wg & 7) * cpx + (wg >> 3);
    int bm = swz / nbn, bn = swz % nbn;

    const u16* Ab = A + (size_t)bm * 128 * K;
    const u16* Bb = BT + (size_t)bn * 128 * K;

    f32x4 acc[4][4];
#pragma unroll
    for (int i = 0; i < 4; ++i)
#pragma unroll
        for (int j = 0; j < 4; ++j) acc[i][j] = f32x4{0.f, 0.f, 0.f, 0.f};

    int L0 = t * 16, L1 = t * 16 + 4096;
    int r0 = L0 >> 6, r1 = L1 >> 6;
    int c0 = ((L0 >> 4) & 3) ^ ((r0 >> 1) & 3);
    int c1 = ((L1 >> 4) & 3) ^ ((r1 >> 1) & 3);
    const u16* a0 = Ab + (size_t)r0 * K + c0 * 8;
    const u16* a1 = Ab + (size_t)r1 * K + c1 * 8;
    const u16* b0 = Bb + (size_t)r0 * K + c0 * 8;
    const u16* b1 = Bb + (size_t)r1 * K + c1 * 8;
    char* la0 = (char*)Asw + L0;
    char* la1 = (char*)Asw + L1;
    char* lb0 = (char*)Bsw + L0;
    char* lb1 = (char*)Bsw + L1;

    int nk = K >> 5;
    for (int kt = 0; kt < nk; ++kt) {
        gload16(a0 + kt * 32, la0);
        gload16(a1 + kt * 32, la1);
        gload16(b0 + kt * 32, lb0);
        gload16(b1 + kt * 32, lb1);
        __syncthreads();
        bf16x8 af[4], bf[4];
#pragma unroll
        for (int fm = 0; fm < 4; ++fm) {
            int row = wm * 64 + fm * 16 + l15;
            int cs = l4 ^ ((row >> 1) & 3);
            af[fm] = *(const bf16x8*)&Asw[row * 32 + cs * 8];
        }
#pragma unroll
        for (int fn = 0; fn < 4; ++fn) {
            int row = wn * 64 + fn * 16 + l15;
            int cs = l4 ^ ((row >> 1) & 3);
            bf[fn] = *(const bf16x8*)&Bsw[row * 32 + cs * 8];
        }
#pragma unroll
        for (int fm = 0; fm < 4; ++fm)
#pragma unroll
            for (int fn = 0; fn < 4; ++fn)
                acc[fm][fn] = __builtin_amdgcn_mfma_f32_16x16x32_bf16(af[fm], bf[fn],
                                                                     acc[fm][fn], 0, 0, 0);
        __syncthreads();
    }
#pragma unroll
    for (int fm = 0; fm < 4; ++fm)
#pragma unroll
        for (int fn = 0; fn < 4; ++fn)
#pragma unroll
            for (int i = 0; i < 4; ++i) {
                int row = bm * 128 + wm * 64 + fm * 16 + l4 * 4 + i;
                int col = bn * 128 + wn * 64 + fn * 16 + l15;
                if constexpr (F32OUT)
                    ((float*)Cv)[(size_t)row * N + col] = acc[fm][fn][i];
                else
                    ((u16*)Cv)[(size_t)row * N + col] = f2bf(acc[fm][fn][i]);
            }
}

// ---------------- repack + RoPE: QKV[s,6144] -> Q[h,s,d], K[hk,s,d], V[hk,s,d] ----
__global__ void repack_rope_k(const u16* __restrict__ QKV, const float* __restrict__ tab,
                              u16* __restrict__ Qo, u16* __restrict__ Ko,
                              u16* __restrict__ Vo) {
    int idx = blockIdx.x * 256 + threadIdx.x;
    if (idx >= SEQ * 48 * 64) return;
    int i = idx & 63;
    int su = idx >> 6;
    int u = su % 48;
    int s = su / 48;
    const float* tp = tab + (s * 64 + i) * 2;
    if (u < 32) {
        const u16* base = QKV + (size_t)s * NQKV + u * 128;
        float x1 = bf2f(base[i]);
        float x2 = bf2f(base[64 + i]);
        float cv = tp[0], sv = tp[1];
        u16* ob = Qo + ((size_t)u * SEQ + s) * 128;
        ob[i] = f2bf(x1 * cv - x2 * sv);
        ob[64 + i] = f2bf(x2 * cv + x1 * sv);
    } else if (u < 40) {
        int hk = u - 32;
        const u16* base = QKV + (size_t)s * NQKV + 4096 + hk * 128;
        float x1 = bf2f(base[i]);
        float x2 = bf2f(base[64 + i]);
        float cv = tp[0], sv = tp[1];
        u16* ob = Ko + ((size_t)hk * SEQ + s) * 128;
        ob[i] = f2bf(x1 * cv - x2 * sv);
        ob[64 + i] = f2bf(x2 * cv + x1 * sv);
    } else {
        int hv = u - 40;
        const u16* base = QKV + (size_t)s * NQKV + 5120 + hv * 128;
        u16* ob = Vo + ((size_t)hv * SEQ + s) * 128;
        ob[i] = base[i];
        ob[64 + i] = base[64 + i];
    }
}

// ---------------- causal GQA flash attention ----------------
__global__ __launch_bounds__(256) void attn_k(const u16* __restrict__ Qg,
                                              const u16* __restrict__ Kg,
                                              const u16* __restrict__ Vg,
                                              u16* __restrict__ ctx) {
    constexpr float SC = 0.08838834764831845f; // 1/sqrt(128)
    __shared__ alignas(16) u16 Klds[32 * 128];
    __shared__ alignas(16) u16 VT[128 * 40];   // V^T, padded stride 40
    __shared__ alignas(16) u16 Plds[4 * 16 * 32];

    int t = threadIdx.x;
    int lane = t & 63, w = t >> 6;
    int l15 = lane & 15, l4 = lane >> 4;
    int q0 = blockIdx.x * 64;
    int h = blockIdx.y;
    int hkv = h >> 2;

    const u16* Qh = Qg + ((size_t)h * SEQ + q0 + w * 16 + l15) * 128;
    bf16x8 qf[4];
#pragma unroll
    for (int ks = 0; ks < 4; ++ks) qf[ks] = *(const bf16x8*)(Qh + ks * 32 + l4 * 8);

    f32x4 o[8];
#pragma unroll
    for (int nf = 0; nf < 8; ++nf) o[nf] = f32x4{0.f, 0.f, 0.f, 0.f};
    float m_i[4], l_i[4];
#pragma unroll
    for (int i = 0; i < 4; ++i) { m_i[i] = -3.0e38f; l_i[i] = 0.f; }

    const u16* Kh = Kg + (size_t)hkv * SEQ * 128;
    const u16* Vh = Vg + (size_t)hkv * SEQ * 128;
    int wqmax = q0 + w * 16 + 15;
    int ntiles = (q0 + 64) >> 5;

    int L0 = t * 16, L1 = t * 16 + 4096;
    int kr0 = L0 >> 8, kr1 = L1 >> 8;
    int kc0 = ((L0 >> 4) & 15) ^ (kr0 & 7);
    int kc1 = ((L1 >> 4) & 15) ^ (kr1 & 7);
    int vr = t & 31, vc0 = (t >> 5) * 8;

    for (int kt = 0; kt < ntiles; ++kt) {
        int kv0 = kt << 5;
        __syncthreads();
        gload16(Kh + (size_t)(kv0 + kr0) * 128 + kc0 * 8, (char*)Klds + L0);
        gload16(Kh + (size_t)(kv0 + kr1) * 128 + kc1 * 8, (char*)Klds + L1);
#pragma unroll
        for (int seg = 0; seg < 2; ++seg) {
            int c = vc0 + seg * 64;
            bf16x8 v = *(const bf16x8*)(Vh + (size_t)(kv0 + vr) * 128 + c);
            u16* vv = (u16*)&v;
#pragma unroll
            for (int j = 0; j < 8; ++j) VT[(c + j) * 40 + vr] = vv[j];
        }
        __syncthreads();
        if (kv0 <= wqmax) {
            f32x4 sa0{0.f, 0.f, 0.f, 0.f}, sa1{0.f, 0.f, 0.f, 0.f};
#pragma unroll
            for (int ks = 0; ks < 4; ++ks) {
                int row = l15;
                int cs = (ks * 4 + l4) ^ (row & 7);
                bf16x8 kf = *(const bf16x8*)&Klds[row * 128 + cs * 8];
                sa0 = __builtin_amdgcn_mfma_f32_16x16x32_bf16(qf[ks], kf, sa0, 0, 0, 0);
            }
#pragma unroll
            for (int ks = 0; ks < 4; ++ks) {
                int row = 16 + l15;
                int cs = (ks * 4 + l4) ^ (row & 7);
                bf16x8 kf = *(const bf16x8*)&Klds[row * 128 + cs * 8];
                sa1 = __builtin_amdgcn_mfma_f32_16x16x32_bf16(qf[ks], kf, sa1, 0, 0, 0);
            }
            float p0[4], p1[4], corr[4];
#pragma unroll
            for (int i = 0; i < 4; ++i) {
                int qrow = q0 + w * 16 + l4 * 4 + i;
                float v0 = sa0[i] * SC;
                float v1 = sa1[i] * SC;
                if (kv0 + l15 > qrow) v0 = -3.0e38f;
                if (kv0 + 16 + l15 > qrow) v1 = -3.0e38f;
                float mx = fmaxf(v0, v1);
                mx = fmaxf(mx, __shfl_xor(mx, 1));
                mx = fmaxf(mx, __shfl_xor(mx, 2));
                mx = fmaxf(mx, __shfl_xor(mx, 4));
                mx = fmaxf(mx, __shfl_xor(mx, 8));
                float mnew = fmaxf(m_i[i], mx);
                corr[i] = __expf(m_i[i] - mnew);
                float a0 = __expf(v0 - mnew);
                float a1 = __expf(v1 - mnew);
                float rs = a0 + a1;
                rs += __shfl_xor(rs, 1);
                rs += __shfl_xor(rs, 2);
                rs += __shfl_xor(rs, 4);
                rs += __shfl_xor(rs, 8);
                l_i[i] = l_i[i] * corr[i] + rs;
                m_i[i] = mnew;
                p0[i] = a0; p1[i] = a1;
            }
#pragma unroll
            for (int nf = 0; nf < 8; ++nf) {
                o[nf][0] *= corr[0]; o[nf][1] *= corr[1];
                o[nf][2] *= corr[2]; o[nf][3] *= corr[3];
            }
            u16* Pw = &Plds[w * 512];
#pragma unroll
            for (int i = 0; i < 4; ++i) {
                int prow = l4 * 4 + i;
                int sw = (prow >> 1) & 3;
                int col0 = l15;
                Pw[prow * 32 + (((col0 >> 3) ^ sw) << 3) + (col0 & 7)] = f2bf(p0[i]);
                int col1 = 16 + l15;
                Pw[prow * 32 + (((col1 >> 3) ^ sw) << 3) + (col1 & 7)] = f2bf(p1[i]);
            }
            asm volatile("s_waitcnt lgkmcnt(0)" ::: "memory");
            bf16x8 pf = *(const bf16x8*)&Pw[l15 * 32 + (l4 ^ ((l15 >> 1) & 3)) * 8];
#pragma unroll
            for (int nf = 0; nf < 8; ++nf) {
                int n = nf * 16 + l15;
                bf16x8 vf = *(const bf16x8*)&VT[n * 40 + l4 * 8];
                o[nf] = __builtin_amdgcn_mfma_f32_16x16x32_bf16(pf, vf, o[nf], 0, 0, 0);
            }
        }
    }
    float inv[4];
#pragma unroll
    for (int i = 0; i < 4; ++i) inv[i] = 1.0f / l_i[i];
#pragma unroll
    for (int nf = 0; nf < 8; ++nf)
#pragma unroll
        for (int i = 0; i < 4; ++i) {
            int qrow = q0 + w * 16 + l4 * 4 + i;
            ctx[(size_t)qrow * 4096 + h * 128 + nf * 16 + l15] = f2bf(o[nf][i] * inv[i]);
        }
}

extern "C" void kernel_launch(void* const* d_in, const int* in_sizes, int n_in,
                              void* d_out, int out_size, void* d_ws, size_t ws_size,
                              hipStream_t stream) {
    const float* hidden = (const float*)d_in[0];   // fp32 (per reference dtype)
    // d_in[1] = sequence_mask (unused by reference math: all-ones + causal)
    const float* Wqkv = (const float*)d_in[2];     // fp32
    const float* Wo = (const float*)d_in[3];       // fp32
    float* out = (float*)d_out;                    // fp32 output
    char* ws = (char*)d_ws;

    // ws layout (bytes) with verified liveness (no overlapping live intervals):
    //   WqkvT  [0, 50331648)          live: transpose1 -> gemm1
    //   Qb     [0, 16777216)          live: repack -> attn   (WqkvT dead)
    //   Kb     [16777216, 20971520)   live: repack -> attn
    //   Vb     [20971520, 25165824)   live: repack -> attn
    //   WoT    [25165824, 58720256)   live: transposeWo -> gemm2 (after repack)
    //   QKV    [50331648, 75497472)   live: gemm1 -> repack
    //   ctx    [58720256, 75497472)   live: attn -> gemm2    (QKV dead, disjoint WoT)
    //   tab    [75497472, 76546048)   live: rope -> repack
    //   hiddenB[76546048, 93323264)   live: cast -> gemm1
    u16* WqkvT   = (u16*)(ws + 0);
    u16* Qb      = (u16*)(ws + 0);
    u16* Kb      = (u16*)(ws + 16777216);
    u16* Vb      = (u16*)(ws + 20971520);
    u16* WoT     = (u16*)(ws + 25165824);
    u16* QKV     = (u16*)(ws + 50331648);
    u16* ctx     = (u16*)(ws + 58720256);
    float* tab   = (float*)(ws + 75497472);
    u16* hiddenB = (u16*)(ws + 76546048);

    rope_table_k<<<512, 256, 0, stream>>>(tab);
    cast_k<<<8192, 256, 0, stream>>>(hidden, hiddenB, 2048 * 4096 / 4);
    transpose_cast_k<<<dim3(96, 64), 256, 0, stream>>>(Wqkv, WqkvT, 4096, 6144);
    gemm_bt_k<false><<<768, 256, 0, stream>>>(hiddenB, WqkvT, QKV, 6144, 4096);
    repack_rope_k<<<24576, 256, 0, stream>>>(QKV, tab, Qb, Kb, Vb);
    transpose_cast_k<<<dim3(64, 64), 256, 0, stream>>>(Wo, WoT, 4096, 4096);
    attn_k<<<dim3(32, 32), 256, 0, stream>>>(Qb, Kb, Vb, ctx);
    gemm_bt_k<true><<<512, 256, 0, stream>>>(ctx, WoT, out, 4096, 4096);
}

// Round 5
// 413.396 us; speedup vs baseline: 1.3503x; 1.3503x over previous
//
#include <hip/hip_runtime.h>

typedef unsigned short u16;
typedef __bf16 bf16x8 __attribute__((ext_vector_type(8)));
typedef float f32x4 __attribute__((ext_vector_type(4)));
typedef u16 u16x4 __attribute__((ext_vector_type(4)));

constexpr int SEQ = 2048;
constexpr int NQKV = 6144; // (32 + 2*8) * 128

__device__ __forceinline__ float bf2f(u16 x) {
    unsigned int u = ((unsigned int)x) << 16;
    return __builtin_bit_cast(float, u);
}
__device__ __forceinline__ u16 f2bf(float f) {
    unsigned int u = __builtin_bit_cast(unsigned int, f);
    u += 0x7FFF + ((u >> 16) & 1);
    return (u16)(u >> 16);
}

__device__ __forceinline__ void gload16(const void* g, void* l) {
    void* gg = const_cast<void*>(g);
    __builtin_amdgcn_global_load_lds(
        (__attribute__((address_space(1))) void*)gg,
        (__attribute__((address_space(3))) void*)l, 16, 0, 0);
}

// ---------------- RoPE table ----------------
__global__ void rope_table_k(float* __restrict__ tab) {
    int idx = blockIdx.x * 256 + threadIdx.x;
    if (idx >= SEQ * 64) return;
    int s = idx >> 6;
    int i = idx & 63;
    float invf = expf(-(float)i * (float)(1.0 / 64.0) * logf(10000.0f));
    float ang = (float)s * invf;
    float sv, cv;
    sincosf(ang, &sv, &cv);
    tab[idx * 2] = cv;
    tab[idx * 2 + 1] = sv;
}

// ---------------- fp32 -> bf16 elementwise cast ----------------
__global__ __launch_bounds__(256) void cast_k(const float* __restrict__ src,
                                              u16* __restrict__ dst, int n4) {
    int i = blockIdx.x * 256 + threadIdx.x;
    if (i >= n4) return;
    f32x4 v = *(const f32x4*)&src[(size_t)i * 4];
    u16x4 o;
#pragma unroll
    for (int j = 0; j < 4; ++j) o[j] = f2bf(v[j]);
    *(u16x4*)&dst[(size_t)i * 4] = o;
}

// ---------------- fp32 transpose+cast (R x C fp32 -> C x R bf16) ----------------
__global__ __launch_bounds__(256) void transpose_cast_k(const float* __restrict__ src,
                                                        u16* __restrict__ dst, int R, int C) {
    __shared__ u16 tile[64][65];
    int t = threadIdx.x;
    int bx = blockIdx.x, by = blockIdx.y;
    int r0 = by * 64, c0 = bx * 64;
#pragma unroll
    for (int it = 0; it < 4; ++it) {
        int row = it * 16 + (t >> 4);
        int col = (t & 15) * 4;
        f32x4 v = *(const f32x4*)&src[(size_t)(r0 + row) * C + c0 + col];
        tile[row][col] = f2bf(v[0]); tile[row][col + 1] = f2bf(v[1]);
        tile[row][col + 2] = f2bf(v[2]); tile[row][col + 3] = f2bf(v[3]);
    }
    __syncthreads();
#pragma unroll
    for (int it = 0; it < 4; ++it) {
        int orow = it * 16 + (t >> 4);
        int ocol = (t & 15) * 4;
        u16x4 v;
        v[0] = tile[ocol][orow]; v[1] = tile[ocol + 1][orow];
        v[2] = tile[ocol + 2][orow]; v[3] = tile[ocol + 3][orow];
        *(u16x4*)&dst[(size_t)(c0 + orow) * R + r0 + ocol] = v;
    }
}

// ---------------- GEMM: C[M,N] = A[M,K] * BT[N,K]^T, bf16 in, fp32 acc ----
template <bool F32OUT>
__global__ __launch_bounds__(256) void gemm_bt_k(const u16* __restrict__ A,
                                                 const u16* __restrict__ BT,
                                                 void* __restrict__ Cv, int N, int K) {
    __shared__ alignas(16) u16 Asw[128 * 32];
    __shared__ alignas(16) u16 Bsw[128 * 32];
    int t = threadIdx.x;
    int lane = t & 63, w = t >> 6;
    int wm = w >> 1, wn = w & 1;
    int l15 = lane & 15, l4 = lane >> 4;

    // XCD-aware swizzle (grids are multiples of 8)
    int nbn = N >> 7;
    int nwg = gridDim.x;
    int wg = blockIdx.x;
    int cpx = nwg >> 3;
    int swz = (wg & 7) * cpx + (wg >> 3);
    int bm = swz / nbn, bn = swz % nbn;

    const u16* Ab = A + (size_t)bm * 128 * K;
    const u16* Bb = BT + (size_t)bn * 128 * K;

    f32x4 acc[4][4];
#pragma unroll
    for (int i = 0; i < 4; ++i)
#pragma unroll
        for (int j = 0; j < 4; ++j) acc[i][j] = f32x4{0.f, 0.f, 0.f, 0.f};

    int L0 = t * 16, L1 = t * 16 + 4096;
    int r0 = L0 >> 6, r1 = L1 >> 6;
    int c0 = ((L0 >> 4) & 3) ^ ((r0 >> 1) & 3);
    int c1 = ((L1 >> 4) & 3) ^ ((r1 >> 1) & 3);
    const u16* a0 = Ab + (size_t)r0 * K + c0 * 8;
    const u16* a1 = Ab + (size_t)r1 * K + c1 * 8;
    const u16* b0 = Bb + (size_t)r0 * K + c0 * 8;
    const u16* b1 = Bb + (size_t)r1 * K + c1 * 8;
    char* la0 = (char*)Asw + L0;
    char* la1 = (char*)Asw + L1;
    char* lb0 = (char*)Bsw + L0;
    char* lb1 = (char*)Bsw + L1;

    int nk = K >> 5;
    for (int kt = 0; kt < nk; ++kt) {
        gload16(a0 + kt * 32, la0);
        gload16(a1 + kt * 32, la1);
        gload16(b0 + kt * 32, lb0);
        gload16(b1 + kt * 32, lb1);
        __syncthreads();
        bf16x8 af[4], bf[4];
#pragma unroll
        for (int fm = 0; fm < 4; ++fm) {
            int row = wm * 64 + fm * 16 + l15;
            int cs = l4 ^ ((row >> 1) & 3);
            af[fm] = *(const bf16x8*)&Asw[row * 32 + cs * 8];
        }
#pragma unroll
        for (int fn = 0; fn < 4; ++fn) {
            int row = wn * 64 + fn * 16 + l15;
            int cs = l4 ^ ((row >> 1) & 3);
            bf[fn] = *(const bf16x8*)&Bsw[row * 32 + cs * 8];
        }
#pragma unroll
        for (int fm = 0; fm < 4; ++fm)
#pragma unroll
            for (int fn = 0; fn < 4; ++fn)
                acc[fm][fn] = __builtin_amdgcn_mfma_f32_16x16x32_bf16(af[fm], bf[fn],
                                                                     acc[fm][fn], 0, 0, 0);
        __syncthreads();
    }
#pragma unroll
    for (int fm = 0; fm < 4; ++fm)
#pragma unroll
        for (int fn = 0; fn < 4; ++fn)
#pragma unroll
            for (int i = 0; i < 4; ++i) {
                int row = bm * 128 + wm * 64 + fm * 16 + l4 * 4 + i;
                int col = bn * 128 + wn * 64 + fn * 16 + l15;
                if constexpr (F32OUT)
                    ((float*)Cv)[(size_t)row * N + col] = acc[fm][fn][i];
                else
                    ((u16*)Cv)[(size_t)row * N + col] = f2bf(acc[fm][fn][i]);
            }
}

// -------- repack + RoPE (vectorized): QKV[s,6144] -> Q[h,s,d], K[hk,s,d], V[hk,s,d] --------
__global__ __launch_bounds__(256) void repack_rope_k(const u16* __restrict__ QKV,
                                                     const float* __restrict__ tab,
                                                     u16* __restrict__ Qo, u16* __restrict__ Ko,
                                                     u16* __restrict__ Vo) {
    int idx = blockIdx.x * 256 + threadIdx.x; // < SEQ*48*16
    int i4 = (idx & 15) * 4;
    int su = idx >> 4;
    int u = su % 48;
    int s = su / 48;
    if (u < 40) {
        const float* tp = tab + (s * 64 + i4) * 2;
        f32x4 t0 = *(const f32x4*)tp;
        f32x4 t1 = *(const f32x4*)(tp + 4);
        float cv[4] = {t0[0], t0[2], t1[0], t1[2]};
        float sv[4] = {t0[1], t0[3], t1[1], t1[3]};
        const u16* base;
        u16* ob;
        if (u < 32) {
            base = QKV + (size_t)s * NQKV + u * 128;
            ob = Qo + ((size_t)u * SEQ + s) * 128;
        } else {
            base = QKV + (size_t)s * NQKV + 4096 + (u - 32) * 128;
            ob = Ko + ((size_t)(u - 32) * SEQ + s) * 128;
        }
        u16x4 x1 = *(const u16x4*)(base + i4);
        u16x4 x2 = *(const u16x4*)(base + 64 + i4);
        u16x4 o1, o2;
#pragma unroll
        for (int j = 0; j < 4; ++j) {
            float a = bf2f(x1[j]), b = bf2f(x2[j]);
            o1[j] = f2bf(a * cv[j] - b * sv[j]);
            o2[j] = f2bf(b * cv[j] + a * sv[j]);
        }
        *(u16x4*)(ob + i4) = o1;
        *(u16x4*)(ob + 64 + i4) = o2;
    } else {
        int hv = u - 40;
        const u16* base = QKV + (size_t)s * NQKV + 5120 + hv * 128;
        u16* ob = Vo + ((size_t)hv * SEQ + s) * 128;
        *(u16x4*)(ob + i4) = *(const u16x4*)(base + i4);
        *(u16x4*)(ob + 64 + i4) = *(const u16x4*)(base + 64 + i4);
    }
}

// ---------------- causal GQA flash attention (paired q-tiles, KVBLK=64) ----------------
__global__ __launch_bounds__(256) void attn_k(const u16* __restrict__ Qg,
                                              const u16* __restrict__ Kg,
                                              const u16* __restrict__ Vg,
                                              u16* __restrict__ ctx) {
    constexpr float SCL2 = 0.08838834764831845f * 1.44269504088896340736f; // 1/sqrt(128)*log2(e)
    constexpr float THR = 11.5f; // defer-max threshold (log2 domain, ~8 nats)
    __shared__ alignas(16) u16 Klds[64 * 128];  // 16 KB, XOR-swizzled
    __shared__ alignas(16) u16 VT[128 * 72];    // 18 KB, V^T stride 72
    __shared__ alignas(16) u16 Plds[4 * 16 * 64]; // 8 KB, per-wave P

    int t = threadIdx.x;
    int lane = t & 63, w = t >> 6;
    int l15 = lane & 15, l4 = lane >> 4;
    int bx = blockIdx.x, h = blockIdx.y, hkv = h >> 2;
    const u16* Kh = Kg + (size_t)hkv * SEQ * 128;
    const u16* Vh = Vg + (size_t)hkv * SEQ * 128;
    u16* Pw = &Plds[w * 1024];

    // K staging addressing: 4 chunks/thread, row-XOR swizzle
    int kr[4], kchs[4];
#pragma unroll
    for (int i2 = 0; i2 < 4; ++i2) {
        int c = t + i2 * 256;
        kr[i2] = c >> 4;
        kchs[i2] = (c & 15) ^ (kr[i2] & 7);
    }
    int vr = t & 63, vcb = (t >> 6) * 32;

    int q0 = bx * 64; // member A; member B = (31-bx)*64
    int ntA = bx + 1; // member A KV tiles; member B has 32-bx; total 33

    bf16x8 qf[4];
    f32x4 o[8];
    float m_i[4], l_i[4];

    auto load_q = [&]() {
        const u16* Qh = Qg + ((size_t)h * SEQ + q0 + w * 16 + l15) * 128;
#pragma unroll
        for (int ks = 0; ks < 4; ++ks) qf[ks] = *(const bf16x8*)(Qh + ks * 32 + l4 * 8);
    };
    auto reset_acc = [&]() {
#pragma unroll
        for (int nf = 0; nf < 8; ++nf) o[nf] = f32x4{0.f, 0.f, 0.f, 0.f};
#pragma unroll
        for (int i = 0; i < 4; ++i) { m_i[i] = -3.0e38f; l_i[i] = 0.f; }
    };
    auto write_ctx = [&]() {
        float inv[4];
#pragma unroll
        for (int i = 0; i < 4; ++i) inv[i] = 1.0f / l_i[i];
#pragma unroll
        for (int nf = 0; nf < 8; ++nf)
#pragma unroll
            for (int i = 0; i < 4; ++i) {
                int qrow = q0 + w * 16 + l4 * 4 + i;
                ctx[(size_t)qrow * 4096 + h * 128 + nf * 16 + l15] = f2bf(o[nf][i] * inv[i]);
            }
    };

    load_q();
    reset_acc();

    for (int tt = 0; tt < 33; ++tt) {
        if (tt == ntA) { // finish member A, switch to member B
            write_ctx();
            q0 = (31 - bx) * 64;
            load_q();
            reset_acc();
        }
        int kv0 = (tt < ntA ? tt : tt - ntA) << 6;

        __syncthreads();
#pragma unroll
        for (int i2 = 0; i2 < 4; ++i2)
            gload16(Kh + (size_t)(kv0 + kr[i2]) * 128 + kchs[i2] * 8,
                    (char*)Klds + (size_t)(t + i2 * 256) * 16);
#pragma unroll
        for (int seg = 0; seg < 4; ++seg) {
            int c0 = vcb + seg * 8;
            bf16x8 v = *(const bf16x8*)(Vh + (size_t)(kv0 + vr) * 128 + c0);
            u16* vv = (u16*)&v;
#pragma unroll
            for (int j = 0; j < 8; ++j) VT[(c0 + j) * 72 + vr] = vv[j];
        }
        __syncthreads();

        // ---- QK^T: sa[cg] covers KV cols cg*16+l15, rows l4*4+i ----
        f32x4 sa[4];
#pragma unroll
        for (int cg = 0; cg < 4; ++cg) {
            sa[cg] = f32x4{0.f, 0.f, 0.f, 0.f};
            int row = cg * 16 + l15;
#pragma unroll
            for (int ks = 0; ks < 4; ++ks) {
                int chs = (ks * 4 + l4) ^ (row & 7);
                bf16x8 kf = *(const bf16x8*)&Klds[row * 128 + chs * 8];
                sa[cg] = __builtin_amdgcn_mfma_f32_16x16x32_bf16(qf[ks], kf, sa[cg], 0, 0, 0);
            }
        }
        // scale into log2 domain
#pragma unroll
        for (int cg = 0; cg < 4; ++cg)
#pragma unroll
            for (int i = 0; i < 4; ++i) sa[cg][i] *= SCL2;
        // causal mask (wave-uniform skip for interior tiles)
        if (kv0 + 63 > q0 + w * 16) {
#pragma unroll
            for (int cg = 0; cg < 4; ++cg) {
                int col = kv0 + cg * 16 + l15;
#pragma unroll
                for (int i = 0; i < 4; ++i) {
                    int qrow = q0 + w * 16 + l4 * 4 + i;
                    if (col > qrow) sa[cg][i] = -3.0e38f;
                }
            }
        }
        // ---- online softmax (log2 domain, defer-max) ----
        float mx[4];
#pragma unroll
        for (int i = 0; i < 4; ++i) {
            float m0 = fmaxf(fmaxf(sa[0][i], sa[1][i]), fmaxf(sa[2][i], sa[3][i]));
            m0 = fmaxf(m0, __shfl_xor(m0, 1));
            m0 = fmaxf(m0, __shfl_xor(m0, 2));
            m0 = fmaxf(m0, __shfl_xor(m0, 4));
            m0 = fmaxf(m0, __shfl_xor(m0, 8));
            mx[i] = m0;
        }
        bool defer = __all((mx[0] <= m_i[0] + THR) & (mx[1] <= m_i[1] + THR) &
                           (mx[2] <= m_i[2] + THR) & (mx[3] <= m_i[3] + THR));
        float corr[4];
#pragma unroll
        for (int i = 0; i < 4; ++i) {
            float mnew = defer ? m_i[i] : fmaxf(m_i[i], mx[i]);
            corr[i] = __builtin_amdgcn_exp2f(m_i[i] - mnew);
            m_i[i] = mnew;
        }
#pragma unroll
        for (int i = 0; i < 4; ++i) {
            int prow = l4 * 4 + i;
            int sw = (prow >> 1) & 3;
            float rs = 0.f;
#pragma unroll
            for (int cg = 0; cg < 4; ++cg) {
                float p = __builtin_amdgcn_exp2f(sa[cg][i] - m_i[i]);
                rs += p;
                int ch = cg * 2 + (l15 >> 3);
                Pw[prow * 64 + ((ch ^ sw) << 3) + (l15 & 7)] = f2bf(p);
            }
            rs += __shfl_xor(rs, 1);
            rs += __shfl_xor(rs, 2);
            rs += __shfl_xor(rs, 4);
            rs += __shfl_xor(rs, 8);
            l_i[i] = l_i[i] * corr[i] + rs;
        }
        if (!defer) {
#pragma unroll
            for (int nf = 0; nf < 8; ++nf) {
                o[nf][0] *= corr[0]; o[nf][1] *= corr[1];
                o[nf][2] *= corr[2]; o[nf][3] *= corr[3];
            }
        }
        // ---- PV ----
        asm volatile("s_waitcnt lgkmcnt(0)" ::: "memory");
#pragma unroll
        for (int kst = 0; kst < 2; ++kst) {
            int chs = (kst * 4 + l4) ^ ((l15 >> 1) & 3);
            bf16x8 pf = *(const bf16x8*)&Pw[l15 * 64 + chs * 8];
#pragma unroll
            for (int nf = 0; nf < 8; ++nf) {
                bf16x8 vf = *(const bf16x8*)&VT[(nf * 16 + l15) * 72 + kst * 32 + l4 * 8];
                o[nf] = __builtin_amdgcn_mfma_f32_16x16x32_bf16(pf, vf, o[nf], 0, 0, 0);
            }
        }
    }
    write_ctx();
}

extern "C" void kernel_launch(void* const* d_in, const int* in_sizes, int n_in,
                              void* d_out, int out_size, void* d_ws, size_t ws_size,
                              hipStream_t stream) {
    const float* hidden = (const float*)d_in[0];   // fp32 (per reference dtype)
    // d_in[1] = sequence_mask (unused by reference math: all-ones + causal)
    const float* Wqkv = (const float*)d_in[2];     // fp32
    const float* Wo = (const float*)d_in[3];       // fp32
    float* out = (float*)d_out;                    // fp32 output
    char* ws = (char*)d_ws;

    // ws layout (bytes) with verified liveness (no overlapping live intervals):
    //   WqkvT  [0, 50331648)          live: transpose1 -> gemm1
    //   Qb     [0, 16777216)          live: repack -> attn   (WqkvT dead)
    //   Kb     [16777216, 20971520)   live: repack -> attn
    //   Vb     [20971520, 25165824)   live: repack -> attn
    //   WoT    [25165824, 58720256)   live: transposeWo -> gemm2 (after repack)
    //   QKV    [50331648, 75497472)   live: gemm1 -> repack
    //   ctx    [58720256, 75497472)   live: attn -> gemm2    (QKV dead, disjoint WoT)
    //   tab    [75497472, 76546048)   live: rope -> repack
    //   hiddenB[76546048, 93323264)   live: cast -> gemm1
    u16* WqkvT   = (u16*)(ws + 0);
    u16* Qb      = (u16*)(ws + 0);
    u16* Kb      = (u16*)(ws + 16777216);
    u16* Vb      = (u16*)(ws + 20971520);
    u16* WoT     = (u16*)(ws + 25165824);
    u16* QKV     = (u16*)(ws + 50331648);
    u16* ctx     = (u16*)(ws + 58720256);
    float* tab   = (float*)(ws + 75497472);
    u16* hiddenB = (u16*)(ws + 76546048);

    rope_table_k<<<512, 256, 0, stream>>>(tab);
    cast_k<<<8192, 256, 0, stream>>>(hidden, hiddenB, 2048 * 4096 / 4);
    transpose_cast_k<<<dim3(96, 64), 256, 0, stream>>>(Wqkv, WqkvT, 4096, 6144);
    gemm_bt_k<false><<<768, 256, 0, stream>>>(hiddenB, WqkvT, QKV, 6144, 4096);
    repack_rope_k<<<6144, 256, 0, stream>>>(QKV, tab, Qb, Kb, Vb);
    transpose_cast_k<<<dim3(64, 64), 256, 0, stream>>>(Wo, WoT, 4096, 4096);
    attn_k<<<dim3(16, 32), 256, 0, stream>>>(Qb, Kb, Vb, ctx);
    gemm_bt_k<true><<<512, 256, 0, stream>>>(ctx, WoT, out, 4096, 4096);
}

// Round 6
// 401.933 us; speedup vs baseline: 1.3888x; 1.0285x over previous
//
#include <hip/hip_runtime.h>

typedef unsigned short u16;
typedef __bf16 bf16x8 __attribute__((ext_vector_type(8)));
typedef float f32x4 __attribute__((ext_vector_type(4)));
typedef u16 u16x4 __attribute__((ext_vector_type(4)));

constexpr int SEQ = 2048;
constexpr int NQKV = 6144; // (32 + 2*8) * 128

__device__ __forceinline__ float bf2f(u16 x) {
    unsigned int u = ((unsigned int)x) << 16;
    return __builtin_bit_cast(float, u);
}
__device__ __forceinline__ u16 f2bf(float f) {
    unsigned int u = __builtin_bit_cast(unsigned int, f);
    u += 0x7FFF + ((u >> 16) & 1);
    return (u16)(u >> 16);
}

__device__ __forceinline__ void gload16(const void* g, void* l) {
    void* gg = const_cast<void*>(g);
    __builtin_amdgcn_global_load_lds(
        (__attribute__((address_space(1))) void*)gg,
        (__attribute__((address_space(3))) void*)l, 16, 0, 0);
}

// counted-vmcnt gate + raw barrier (NO vmcnt(0) drain in steady state)
__device__ __forceinline__ void gatebar(int G) {
    if (G == 3) asm volatile("s_waitcnt vmcnt(3)" ::: "memory");
    else if (G == 2) asm volatile("s_waitcnt vmcnt(2)" ::: "memory");
    else asm volatile("s_waitcnt vmcnt(0)" ::: "memory");
    __builtin_amdgcn_sched_barrier(0);
    __builtin_amdgcn_s_barrier();
    __builtin_amdgcn_sched_barrier(0);
}

// ---------------- RoPE table ----------------
__global__ void rope_table_k(float* __restrict__ tab) {
    int idx = blockIdx.x * 256 + threadIdx.x;
    if (idx >= SEQ * 64) return;
    int s = idx >> 6;
    int i = idx & 63;
    float invf = expf(-(float)i * (float)(1.0 / 64.0) * logf(10000.0f));
    float ang = (float)s * invf;
    float sv, cv;
    sincosf(ang, &sv, &cv);
    tab[idx * 2] = cv;
    tab[idx * 2 + 1] = sv;
}

// ---------------- fp32 -> bf16 elementwise cast ----------------
__global__ __launch_bounds__(256) void cast_k(const float* __restrict__ src,
                                              u16* __restrict__ dst, int n4) {
    int i = blockIdx.x * 256 + threadIdx.x;
    if (i >= n4) return;
    f32x4 v = *(const f32x4*)&src[(size_t)i * 4];
    u16x4 o;
#pragma unroll
    for (int j = 0; j < 4; ++j) o[j] = f2bf(v[j]);
    *(u16x4*)&dst[(size_t)i * 4] = o;
}

// ---------------- fp32 transpose+cast (R x C fp32 -> C x R bf16) ----------------
__global__ __launch_bounds__(256) void transpose_cast_k(const float* __restrict__ src,
                                                        u16* __restrict__ dst, int R, int C) {
    __shared__ u16 tile[64][65];
    int t = threadIdx.x;
    int bx = blockIdx.x, by = blockIdx.y;
    int r0 = by * 64, c0 = bx * 64;
#pragma unroll
    for (int it = 0; it < 4; ++it) {
        int row = it * 16 + (t >> 4);
        int col = (t & 15) * 4;
        f32x4 v = *(const f32x4*)&src[(size_t)(r0 + row) * C + c0 + col];
        tile[row][col] = f2bf(v[0]); tile[row][col + 1] = f2bf(v[1]);
        tile[row][col + 2] = f2bf(v[2]); tile[row][col + 3] = f2bf(v[3]);
    }
    __syncthreads();
#pragma unroll
    for (int it = 0; it < 4; ++it) {
        int orow = it * 16 + (t >> 4);
        int ocol = (t & 15) * 4;
        u16x4 v;
        v[0] = tile[ocol][orow]; v[1] = tile[ocol + 1][orow];
        v[2] = tile[ocol + 2][orow]; v[3] = tile[ocol + 3][orow];
        *(u16x4*)&dst[(size_t)(c0 + orow) * R + r0 + ocol] = v;
    }
}

// ---- pipelined GEMM: C[M,N] = A[M,K] * BT[N,K]^T, bf16 in, fp32 acc ----
// BM=128, BN=NF*64, BK=32; 3 LDS buffers; counted vmcnt; raw barriers.
template <int NF, bool F32OUT>
__global__ __launch_bounds__(512, 4) void gemm_pipe_k(const u16* __restrict__ A,
                                                      const u16* __restrict__ BT,
                                                      void* __restrict__ Cv, int N, int K) {
    constexpr int BN = NF * 64;
    constexpr int SA = 128 * 64;      // bytes per A K-tile (128 rows x 32k x 2B)
    constexpr int SB = BN * 64;       // bytes per B K-tile
    constexpr int SBUF = SA + SB;
    __shared__ alignas(16) char lds[3 * SBUF];

    int t = threadIdx.x;
    int lane = t & 63, w = t >> 6;
    int wr = w >> 2, wc = w & 3;
    int l15 = lane & 15, l4 = lane >> 4;

    int nbn = N / BN;
    int wg = blockIdx.x;
    int cpx = gridDim.x >> 3;
    int swz = (wg & 7) * cpx + (wg >> 3);
    int bm = swz / nbn, bn = swz % nbn;

    const u16* Ab = A + (size_t)bm * 128 * K;
    const u16* Bb = BT + (size_t)bn * BN * K;

    // staging addressing (pre-swizzled global source, linear LDS dest)
    int ar = t >> 2;
    int akc = (t & 3) ^ ((ar >> 1) & 3);
    const u16* ga = Ab + (size_t)ar * K + akc * 8;
    int br0 = t >> 2;
    int bk0 = (t & 3) ^ ((br0 >> 1) & 3);
    const u16* gb0 = Bb + (size_t)br0 * K + bk0 * 8;
    int bc1 = 512 + t;
    int br1 = bc1 >> 2;
    int bk1 = (bc1 & 3) ^ ((br1 >> 1) & 3);
    const u16* gb1 = Bb + (size_t)br1 * K + bk1 * 8;
    bool hasB1 = (NF == 3) && (w < 4); // wave-uniform
    int myG = (NF == 3) ? ((w < 4) ? 3 : 2) : 2; // vmem issues per tile per wave

    auto stage = [&](int v) {
        int b = v - (v / 3) * 3;
        char* LA = lds + b * SBUF;
        char* LB = LA + SA;
        int ko = v * 32;
        gload16(ga + ko, LA + t * 16);
        gload16(gb0 + ko, LB + t * 16);
        if (NF == 3) {
            if (hasB1) gload16(gb1 + ko, LB + bc1 * 16);
        }
    };

    f32x4 acc[4][NF];
#pragma unroll
    for (int i = 0; i < 4; ++i)
#pragma unroll
        for (int j = 0; j < NF; ++j) acc[i][j] = f32x4{0.f, 0.f, 0.f, 0.f};

    // fragment read offsets (loop-invariant)
    int arow[4], akk[4];
#pragma unroll
    for (int fm = 0; fm < 4; ++fm) {
        arow[fm] = wr * 64 + fm * 16 + l15;
        akk[fm] = l4 ^ ((arow[fm] >> 1) & 3);
    }
    int brow[NF], bkk[NF];
#pragma unroll
    for (int fn = 0; fn < NF; ++fn) {
        brow[fn] = wc * (NF * 16) + fn * 16 + l15;
        bkk[fn] = l4 ^ ((brow[fn] >> 1) & 3);
    }

    int nk = K >> 5;
    stage(0);
    stage(1);
    gatebar(myG); // tile 0 resident; tile 1 may fly

    int b = 0;
    for (int v = 0; v < nk; ++v) {
        const u16* LA = (const u16*)(lds + b * SBUF);
        const u16* LB = LA + SA / 2; // u16 units
        if (v + 2 < nk) stage(v + 2);
        bf16x8 bf[NF];
#pragma unroll
        for (int fn = 0; fn < NF; ++fn)
            bf[fn] = *(const bf16x8*)&LB[brow[fn] * 32 + bkk[fn] * 8];
        __builtin_amdgcn_s_setprio(1);
#pragma unroll
        for (int fm = 0; fm < 4; ++fm) {
            bf16x8 af = *(const bf16x8*)&LA[arow[fm] * 32 + akk[fm] * 8];
#pragma unroll
            for (int fn = 0; fn < NF; ++fn)
                acc[fm][fn] = __builtin_amdgcn_mfma_f32_16x16x32_bf16(af, bf[fn],
                                                                     acc[fm][fn], 0, 0, 0);
        }
        __builtin_amdgcn_s_setprio(0);
        if (v < nk - 1) gatebar((v + 2 < nk) ? myG : 0);
        b = (b == 2) ? 0 : b + 1;
    }

#pragma unroll
    for (int fm = 0; fm < 4; ++fm)
#pragma unroll
        for (int fn = 0; fn < NF; ++fn)
#pragma unroll
            for (int i = 0; i < 4; ++i) {
                int row = bm * 128 + wr * 64 + fm * 16 + l4 * 4 + i;
                int col = bn * BN + wc * (NF * 16) + fn * 16 + l15;
                if constexpr (F32OUT)
                    ((float*)Cv)[(size_t)row * N + col] = acc[fm][fn][i];
                else
                    ((u16*)Cv)[(size_t)row * N + col] = f2bf(acc[fm][fn][i]);
            }
}

// -------- repack + RoPE (vectorized): QKV[s,6144] -> Q[h,s,d], K[hk,s,d], V[hk,s,d] --------
__global__ __launch_bounds__(256) void repack_rope_k(const u16* __restrict__ QKV,
                                                     const float* __restrict__ tab,
                                                     u16* __restrict__ Qo, u16* __restrict__ Ko,
                                                     u16* __restrict__ Vo) {
    int idx = blockIdx.x * 256 + threadIdx.x; // < SEQ*48*16
    int i4 = (idx & 15) * 4;
    int su = idx >> 4;
    int u = su % 48;
    int s = su / 48;
    if (u < 40) {
        const float* tp = tab + (s * 64 + i4) * 2;
        f32x4 t0 = *(const f32x4*)tp;
        f32x4 t1 = *(const f32x4*)(tp + 4);
        float cv[4] = {t0[0], t0[2], t1[0], t1[2]};
        float sv[4] = {t0[1], t0[3], t1[1], t1[3]};
        const u16* base;
        u16* ob;
        if (u < 32) {
            base = QKV + (size_t)s * NQKV + u * 128;
            ob = Qo + ((size_t)u * SEQ + s) * 128;
        } else {
            base = QKV + (size_t)s * NQKV + 4096 + (u - 32) * 128;
            ob = Ko + ((size_t)(u - 32) * SEQ + s) * 128;
        }
        u16x4 x1 = *(const u16x4*)(base + i4);
        u16x4 x2 = *(const u16x4*)(base + 64 + i4);
        u16x4 o1, o2;
#pragma unroll
        for (int j = 0; j < 4; ++j) {
            float a = bf2f(x1[j]), b = bf2f(x2[j]);
            o1[j] = f2bf(a * cv[j] - b * sv[j]);
            o2[j] = f2bf(b * cv[j] + a * sv[j]);
        }
        *(u16x4*)(ob + i4) = o1;
        *(u16x4*)(ob + 64 + i4) = o2;
    } else {
        int hv = u - 40;
        const u16* base = QKV + (size_t)s * NQKV + 5120 + hv * 128;
        u16* ob = Vo + ((size_t)hv * SEQ + s) * 128;
        *(u16x4*)(ob + i4) = *(const u16x4*)(base + i4);
        *(u16x4*)(ob + 64 + i4) = *(const u16x4*)(base + 64 + i4);
    }
}

// ---------------- causal GQA flash attention (paired q-tiles, KVBLK=64) ----------------
__global__ __launch_bounds__(256) void attn_k(const u16* __restrict__ Qg,
                                              const u16* __restrict__ Kg,
                                              const u16* __restrict__ Vg,
                                              u16* __restrict__ ctx) {
    constexpr float SCL2 = 0.08838834764831845f * 1.44269504088896340736f; // 1/sqrt(128)*log2(e)
    constexpr float THR = 11.5f; // defer-max threshold (log2 domain, ~8 nats)
    __shared__ alignas(16) u16 Klds[64 * 128];  // 16 KB, XOR-swizzled
    __shared__ alignas(16) u16 VT[128 * 72];    // 18 KB, V^T stride 72
    __shared__ alignas(16) u16 Plds[4 * 16 * 64]; // 8 KB, per-wave P

    int t = threadIdx.x;
    int lane = t & 63, w = t >> 6;
    int l15 = lane & 15, l4 = lane >> 4;
    int bx = blockIdx.x, h = blockIdx.y, hkv = h >> 2;
    const u16* Kh = Kg + (size_t)hkv * SEQ * 128;
    const u16* Vh = Vg + (size_t)hkv * SEQ * 128;
    u16* Pw = &Plds[w * 1024];

    // K staging addressing: 4 chunks/thread, row-XOR swizzle
    int kr[4], kchs[4];
#pragma unroll
    for (int i2 = 0; i2 < 4; ++i2) {
        int c = t + i2 * 256;
        kr[i2] = c >> 4;
        kchs[i2] = (c & 15) ^ (kr[i2] & 7);
    }
    int vr = t & 63, vcb = (t >> 6) * 32;

    int q0 = bx * 64; // member A; member B = (31-bx)*64
    int ntA = bx + 1; // member A KV tiles; member B has 32-bx; total 33

    bf16x8 qf[4];
    f32x4 o[8];
    float m_i[4], l_i[4];

    auto load_q = [&]() {
        const u16* Qh = Qg + ((size_t)h * SEQ + q0 + w * 16 + l15) * 128;
#pragma unroll
        for (int ks = 0; ks < 4; ++ks) qf[ks] = *(const bf16x8*)(Qh + ks * 32 + l4 * 8);
    };
    auto reset_acc = [&]() {
#pragma unroll
        for (int nf = 0; nf < 8; ++nf) o[nf] = f32x4{0.f, 0.f, 0.f, 0.f};
#pragma unroll
        for (int i = 0; i < 4; ++i) { m_i[i] = -3.0e38f; l_i[i] = 0.f; }
    };
    auto write_ctx = [&]() {
        float inv[4];
#pragma unroll
        for (int i = 0; i < 4; ++i) inv[i] = 1.0f / l_i[i];
#pragma unroll
        for (int nf = 0; nf < 8; ++nf)
#pragma unroll
            for (int i = 0; i < 4; ++i) {
                int qrow = q0 + w * 16 + l4 * 4 + i;
                ctx[(size_t)qrow * 4096 + h * 128 + nf * 16 + l15] = f2bf(o[nf][i] * inv[i]);
            }
    };

    load_q();
    reset_acc();

    for (int tt = 0; tt < 33; ++tt) {
        if (tt == ntA) { // finish member A, switch to member B
            write_ctx();
            q0 = (31 - bx) * 64;
            load_q();
            reset_acc();
        }
        int kv0 = (tt < ntA ? tt : tt - ntA) << 6;

        __syncthreads();
#pragma unroll
        for (int i2 = 0; i2 < 4; ++i2)
            gload16(Kh + (size_t)(kv0 + kr[i2]) * 128 + kchs[i2] * 8,
                    (char*)Klds + (size_t)(t + i2 * 256) * 16);
#pragma unroll
        for (int seg = 0; seg < 4; ++seg) {
            int c0 = vcb + seg * 8;
            bf16x8 v = *(const bf16x8*)(Vh + (size_t)(kv0 + vr) * 128 + c0);
            u16* vv = (u16*)&v;
#pragma unroll
            for (int j = 0; j < 8; ++j) VT[(c0 + j) * 72 + vr] = vv[j];
        }
        __syncthreads();

        // ---- QK^T: sa[cg] covers KV cols cg*16+l15, rows l4*4+i ----
        f32x4 sa[4];
#pragma unroll
        for (int cg = 0; cg < 4; ++cg) {
            sa[cg] = f32x4{0.f, 0.f, 0.f, 0.f};
            int row = cg * 16 + l15;
#pragma unroll
            for (int ks = 0; ks < 4; ++ks) {
                int chs = (ks * 4 + l4) ^ (row & 7);
                bf16x8 kf = *(const bf16x8*)&Klds[row * 128 + chs * 8];
                sa[cg] = __builtin_amdgcn_mfma_f32_16x16x32_bf16(qf[ks], kf, sa[cg], 0, 0, 0);
            }
        }
        // scale into log2 domain
#pragma unroll
        for (int cg = 0; cg < 4; ++cg)
#pragma unroll
            for (int i = 0; i < 4; ++i) sa[cg][i] *= SCL2;
        // causal mask (wave-uniform skip for interior tiles)
        if (kv0 + 63 > q0 + w * 16) {
#pragma unroll
            for (int cg = 0; cg < 4; ++cg) {
                int col = kv0 + cg * 16 + l15;
#pragma unroll
                for (int i = 0; i < 4; ++i) {
                    int qrow = q0 + w * 16 + l4 * 4 + i;
                    if (col > qrow) sa[cg][i] = -3.0e38f;
                }
            }
        }
        // ---- online softmax (log2 domain, defer-max) ----
        float mx[4];
#pragma unroll
        for (int i = 0; i < 4; ++i) {
            float m0 = fmaxf(fmaxf(sa[0][i], sa[1][i]), fmaxf(sa[2][i], sa[3][i]));
            m0 = fmaxf(m0, __shfl_xor(m0, 1));
            m0 = fmaxf(m0, __shfl_xor(m0, 2));
            m0 = fmaxf(m0, __shfl_xor(m0, 4));
            m0 = fmaxf(m0, __shfl_xor(m0, 8));
            mx[i] = m0;
        }
        bool defer = __all((mx[0] <= m_i[0] + THR) & (mx[1] <= m_i[1] + THR) &
                           (mx[2] <= m_i[2] + THR) & (mx[3] <= m_i[3] + THR));
        float corr[4];
#pragma unroll
        for (int i = 0; i < 4; ++i) {
            float mnew = defer ? m_i[i] : fmaxf(m_i[i], mx[i]);
            corr[i] = __builtin_amdgcn_exp2f(m_i[i] - mnew);
            m_i[i] = mnew;
        }
#pragma unroll
        for (int i = 0; i < 4; ++i) {
            int prow = l4 * 4 + i;
            int sw = (prow >> 1) & 3;
            float rs = 0.f;
#pragma unroll
            for (int cg = 0; cg < 4; ++cg) {
                float p = __builtin_amdgcn_exp2f(sa[cg][i] - m_i[i]);
                rs += p;
                int ch = cg * 2 + (l15 >> 3);
                Pw[prow * 64 + ((ch ^ sw) << 3) + (l15 & 7)] = f2bf(p);
            }
            rs += __shfl_xor(rs, 1);
            rs += __shfl_xor(rs, 2);
            rs += __shfl_xor(rs, 4);
            rs += __shfl_xor(rs, 8);
            l_i[i] = l_i[i] * corr[i] + rs;
        }
        if (!defer) {
#pragma unroll
            for (int nf = 0; nf < 8; ++nf) {
                o[nf][0] *= corr[0]; o[nf][1] *= corr[1];
                o[nf][2] *= corr[2]; o[nf][3] *= corr[3];
            }
        }
        // ---- PV ----
        asm volatile("s_waitcnt lgkmcnt(0)" ::: "memory");
#pragma unroll
        for (int kst = 0; kst < 2; ++kst) {
            int chs = (kst * 4 + l4) ^ ((l15 >> 1) & 3);
            bf16x8 pf = *(const bf16x8*)&Pw[l15 * 64 + chs * 8];
#pragma unroll
            for (int nf = 0; nf < 8; ++nf) {
                bf16x8 vf = *(const bf16x8*)&VT[(nf * 16 + l15) * 72 + kst * 32 + l4 * 8];
                o[nf] = __builtin_amdgcn_mfma_f32_16x16x32_bf16(pf, vf, o[nf], 0, 0, 0);
            }
        }
    }
    write_ctx();
}

extern "C" void kernel_launch(void* const* d_in, const int* in_sizes, int n_in,
                              void* d_out, int out_size, void* d_ws, size_t ws_size,
                              hipStream_t stream) {
    const float* hidden = (const float*)d_in[0];   // fp32 (per reference dtype)
    // d_in[1] = sequence_mask (unused by reference math: all-ones + causal)
    const float* Wqkv = (const float*)d_in[2];     // fp32
    const float* Wo = (const float*)d_in[3];       // fp32
    float* out = (float*)d_out;                    // fp32 output
    char* ws = (char*)d_ws;

    // ws layout (bytes) with verified liveness (no overlapping live intervals):
    u16* WqkvT   = (u16*)(ws + 0);           // transpose1 -> gemm1
    u16* Qb      = (u16*)(ws + 0);           // repack -> attn (WqkvT dead)
    u16* Kb      = (u16*)(ws + 16777216);
    u16* Vb      = (u16*)(ws + 20971520);
    u16* WoT     = (u16*)(ws + 25165824);    // transposeWo -> gemm2
    u16* QKV     = (u16*)(ws + 50331648);    // gemm1 -> repack
    u16* ctx     = (u16*)(ws + 58720256);    // attn -> gemm2
    float* tab   = (float*)(ws + 75497472);  // rope -> repack
    u16* hiddenB = (u16*)(ws + 76546048);    // cast -> gemm1

    rope_table_k<<<512, 256, 0, stream>>>(tab);
    cast_k<<<8192, 256, 0, stream>>>(hidden, hiddenB, 2048 * 4096 / 4);
    transpose_cast_k<<<dim3(96, 64), 256, 0, stream>>>(Wqkv, WqkvT, 4096, 6144);
    gemm_pipe_k<3, false><<<512, 512, 0, stream>>>(hiddenB, WqkvT, QKV, 6144, 4096);
    repack_rope_k<<<6144, 256, 0, stream>>>(QKV, tab, Qb, Kb, Vb);
    transpose_cast_k<<<dim3(64, 64), 256, 0, stream>>>(Wo, WoT, 4096, 4096);
    attn_k<<<dim3(16, 32), 256, 0, stream>>>(Qb, Kb, Vb, ctx);
    gemm_pipe_k<2, true><<<512, 512, 0, stream>>>(ctx, WoT, out, 4096, 4096);
}